// Round 3
// baseline (531.375 us; speedup 1.0000x reference)
//
#include <hip/hip_runtime.h>
#include <math.h>

#define N_NODES 524288
#define BATCH   4096
#define HID     128
#define SMAX    192            // chunk rows staged in LDS
#define LROW    136            // ushorts per LDS row (272 B: 16B-aligned, bank-optimal)

typedef __attribute__((ext_vector_type(8))) short bf16x8;
typedef __attribute__((ext_vector_type(4))) float f32x4;

__device__ __forceinline__ unsigned short f2bf(float f) {
  unsigned int u = __float_as_uint(f);
  u = (u + 0x7FFFu + ((u >> 16) & 1u)) >> 16;   // RNE
  return (unsigned short)u;
}

// K0: seg_starts[b] = lower_bound(bb, b); starts[B] = N. bb is sorted.
__global__ __launch_bounds__(256) void k_bounds(
    const int* __restrict__ bb, int* __restrict__ starts, int N, int B)
{
  const int i = blockIdx.x * blockDim.x + threadIdx.x;
  if (i > N) return;
  const int prev = (i == 0) ? -1 : bb[i - 1];
  const int cur  = (i == N) ? B  : bb[i];
  for (int b = prev + 1; b <= cur && b <= B; ++b) starts[b] = i;
}

// K1: fused attention-score MLP + segment softmax + weighted pooling.
// One block (4 waves) per segment; ball rows staged to LDS bf16 once.
__global__ __launch_bounds__(256, 2) void k_fused(
    const float* __restrict__ ball, const int* __restrict__ starts,
    const float* __restrict__ w1, const float* __restrict__ b1,
    const float* __restrict__ w2, const float* __restrict__ b2,
    float* __restrict__ pooled)
{
  __shared__ unsigned short lds_ball[SMAX * LROW];    // 52224 B
  __shared__ float sc[SMAX];                          // scores -> weights
  __shared__ float2 pr[4][64];                        // pooling partials
  __shared__ float bcast0;                            // rescale factor

  const int b    = blockIdx.x;
  const int tid  = threadIdx.x;
  const int lane = tid & 63;
  const int wv   = tid >> 6;
  const int m16  = lane & 15;
  const int quad = lane >> 4;

  const int start = starts[b];
  const int end   = starts[b + 1];

  // W1 fragments: B[k][n], n = t*16+m16, k = s*32+quad*8+j (L2-cached, 32 KB)
  bf16x8 fb[4][4];
  #pragma unroll
  for (int t = 0; t < 4; ++t) {
    const int n = t * 16 + m16;
    #pragma unroll
    for (int s = 0; s < 4; ++s) {
      const int k0 = s * 32 + quad * 8;
      bf16x8 v;
      #pragma unroll
      for (int j = 0; j < 8; ++j) v[j] = (short)f2bf(w1[(k0 + j) * 64 + n]);
      fb[t][s] = v;
    }
  }
  float b1v[4], w2v[4];
  #pragma unroll
  for (int t = 0; t < 4; ++t) { b1v[t] = b1[t*16 + m16]; w2v[t] = w2[t*16 + m16]; }
  const float b2v = b2[0];

  float m_run = -INFINITY, d_run = 0.f;   // online-softmax state (wave 0)
  const int c2 = tid & 63, qr = tid >> 6; // pooling: col-pair / row-quarter
  float2 acc = make_float2(0.f, 0.f);

  for (int c0 = start; c0 < end; c0 += SMAX) {
    const int Sc = min(SMAX, end - c0);
    __syncthreads();   // LDS reuse guard vs previous chunk's pooling reads

    // ---- stage Sc rows of ball -> LDS bf16 (coalesced float4 reads) ----
    for (int f = tid; f < Sc * 32; f += 256) {
      const int r = f >> 5, k4 = f & 31;
      const float4 v = *(const float4*)(ball + (size_t)(c0 + r) * HID + k4 * 4);
      ushort4 h;
      h.x = f2bf(v.x); h.y = f2bf(v.y); h.z = f2bf(v.z); h.w = f2bf(v.w);
      *(ushort4*)&lds_ball[r * LROW + k4 * 4] = h;
    }
    __syncthreads();

    // ---- scores via MFMA: tiles of 16 rows ----
    const int nt = (Sc + 15) >> 4;
    for (int tile = wv; tile < nt; tile += 4) {
      const int row = tile * 16 + m16;
      f32x4 a0 = {0,0,0,0}, a1 = {0,0,0,0}, a2 = {0,0,0,0}, a3 = {0,0,0,0};
      #pragma unroll
      for (int s = 0; s < 4; ++s) {
        bf16x8 fa = *(const bf16x8*)&lds_ball[row * LROW + s * 32 + quad * 8];
        a0 = __builtin_amdgcn_mfma_f32_16x16x32_bf16(fa, fb[0][s], a0, 0,0,0);
        a1 = __builtin_amdgcn_mfma_f32_16x16x32_bf16(fa, fb[1][s], a1, 0,0,0);
        a2 = __builtin_amdgcn_mfma_f32_16x16x32_bf16(fa, fb[2][s], a2, 0,0,0);
        a3 = __builtin_amdgcn_mfma_f32_16x16x32_bf16(fa, fb[3][s], a3, 0,0,0);
      }
      #pragma unroll
      for (int r = 0; r < 4; ++r) {
        float p = tanhf(a0[r] + b1v[0]) * w2v[0]
                + tanhf(a1[r] + b1v[1]) * w2v[1]
                + tanhf(a2[r] + b1v[2]) * w2v[2]
                + tanhf(a3[r] + b1v[3]) * w2v[3];
        p += __shfl_xor(p, 1); p += __shfl_xor(p, 2);
        p += __shfl_xor(p, 4); p += __shfl_xor(p, 8);
        const int orow = tile * 16 + quad * 4 + r;
        if (m16 == 0 && orow < Sc) sc[orow] = p + b2v;
      }
    }
    __syncthreads();

    // ---- online softmax update (wave 0 only) ----
    if (wv == 0) {
      float v[3], mc = -INFINITY;
      #pragma unroll
      for (int k = 0; k < 3; ++k) {
        const int i = lane + 64 * k;
        v[k] = (i < Sc) ? sc[i] : -INFINITY;
        mc = fmaxf(mc, v[k]);
      }
      #pragma unroll
      for (int o = 32; o; o >>= 1) mc = fmaxf(mc, __shfl_xor(mc, o));
      const float m_new = fmaxf(m_run, mc);
      const float factor = expf(m_run - m_new);    // first chunk: exp(-inf)=0
      float dc = 0.f;
      #pragma unroll
      for (int k = 0; k < 3; ++k) {
        const int i = lane + 64 * k;
        if (i < Sc) { const float e = expf(v[k] - m_new); sc[i] = e; dc += e; }
      }
      #pragma unroll
      for (int o = 32; o; o >>= 1) dc += __shfl_xor(dc, o);
      d_run = d_run * factor + dc;
      m_run = m_new;
      if (lane == 0) bcast0 = factor;
    }
    __syncthreads();

    // ---- pooling accumulate from LDS (b32 reads, 2-way = free) ----
    const float factor = bcast0;
    acc.x *= factor; acc.y *= factor;
    const unsigned int* l32 = (const unsigned int*)lds_ball;
    for (int r = qr; r < Sc; r += 4) {
      const float w = sc[r];
      const unsigned int u = l32[r * (LROW / 2) + c2];
      const float lo = __uint_as_float(u << 16);
      const float hi = __uint_as_float(u & 0xFFFF0000u);
      acc.x += w * lo; acc.y += w * hi;
    }
  }

  pr[qr][c2] = acc;
  __syncthreads();
  if (tid < 64) {   // wave 0 holds d_run
    const float inv = (d_run > 0.f) ? 1.f / d_run : 0.f;
    float2 s0 = pr[0][tid], s1 = pr[1][tid], s2 = pr[2][tid], s3 = pr[3][tid];
    float2 o;
    o.x = (s0.x + s1.x + s2.x + s3.x) * inv;
    o.y = (s0.y + s1.y + s2.y + s3.y) * inv;
    ((float2*)(pooled + (size_t)b * HID))[tid] = o;
  }
}

// K3: h = [query|pooled]@comb_w + comb_b -> LN -> GELU(exact) -> two heads.
__global__ __launch_bounds__(128) void k_combine(
    const float* __restrict__ query, const float* __restrict__ pooled,
    const float* __restrict__ cw, const float* __restrict__ cb,
    const float* __restrict__ lg, const float* __restrict__ lb,
    const float* __restrict__ bw1, const float* __restrict__ bb1,
    const float* __restrict__ bw2, const float* __restrict__ bb2,
    const float* __restrict__ ww1, const float* __restrict__ wb1,
    const float* __restrict__ ww2, const float* __restrict__ wb2,
    float* __restrict__ out)
{
  __shared__ float in_lds[256][8];
  __shared__ float h_lds[128][8];
  __shared__ float part[2][2][8];
  const int tid  = threadIdx.x;
  const int row0 = blockIdx.x * 8;

  for (int idx = tid; idx < 2048; idx += 128) {
    const int k = idx >> 3, r = idx & 7;
    float v = (k < 128) ? query[(size_t)(row0 + r) * 128 + k]
                        : pooled[(size_t)(row0 + r) * 128 + (k - 128)];
    in_lds[k][r] = v;
  }
  __syncthreads();

  const int j = tid;
  float acc[8];
  const float cbj = cb[j];
  #pragma unroll
  for (int r = 0; r < 8; ++r) acc[r] = cbj;
  for (int k = 0; k < 256; ++k) {
    const float w = cw[k * 128 + j];
    #pragma unroll
    for (int r = 0; r < 8; ++r) acc[r] = fmaf(in_lds[k][r], w, acc[r]);
  }

  const int wv = tid >> 6, ln = tid & 63;
  #pragma unroll
  for (int r = 0; r < 8; ++r) {
    float v = acc[r], v2 = v * v;
    #pragma unroll
    for (int o = 32; o; o >>= 1) { v += __shfl_xor(v, o); v2 += __shfl_xor(v2, o); }
    if (ln == 0) { part[0][wv][r] = v; part[1][wv][r] = v2; }
  }
  __syncthreads();
  const float gj = lg[j], bj = lb[j];
  #pragma unroll
  for (int r = 0; r < 8; ++r) {
    const float S = part[0][0][r] + part[0][1][r];
    const float Q = part[1][0][r] + part[1][1][r];
    const float mean = S * (1.f / 128.f);
    const float var  = Q * (1.f / 128.f) - mean * mean;
    const float rs   = rsqrtf(var + 1e-5f);
    float x = (acc[r] - mean) * rs * gj + bj;
    x = 0.5f * x * (1.f + erff(x * 0.70710678118654752f));   // exact GELU
    h_lds[j][r] = x;
  }
  __syncthreads();

  const float* W1 = wv ? ww1 : bw1;
  const float* B1 = wv ? wb1 : bb1;
  const float* W2 = wv ? ww2 : bw2;
  const float  B2 = wv ? wb2[0] : bb2[0];
  float t[8];
  const float b1l = B1[ln];
  #pragma unroll
  for (int r = 0; r < 8; ++r) t[r] = b1l;
  for (int k = 0; k < 128; ++k) {
    const float w = W1[k * 64 + ln];
    #pragma unroll
    for (int r = 0; r < 8; ++r) t[r] = fmaf(h_lds[k][r], w, t[r]);
  }
  const float w2l = W2[ln];
  #pragma unroll
  for (int r = 0; r < 8; ++r) {
    float o = fmaxf(t[r], 0.f) * w2l;
    #pragma unroll
    for (int m = 32; m; m >>= 1) o += __shfl_xor(o, m);
    if (ln == 0) out[wv * BATCH + row0 + r] = o + B2;
  }
}

extern "C" void kernel_launch(void* const* d_in, const int* in_sizes, int n_in,
                              void* d_out, int out_size, void* d_ws, size_t ws_size,
                              hipStream_t stream)
{
  const float* query = (const float*)d_in[0];
  const float* ball  = (const float*)d_in[1];
  const int*   bb    = (const int*)  d_in[2];
  const float* aw1   = (const float*)d_in[3];
  const float* ab1   = (const float*)d_in[4];
  const float* aw2   = (const float*)d_in[5];
  const float* ab2   = (const float*)d_in[6];
  const float* cw    = (const float*)d_in[7];
  const float* cb    = (const float*)d_in[8];
  const float* lg    = (const float*)d_in[9];
  const float* lbeta = (const float*)d_in[10];
  const float* bw1   = (const float*)d_in[11];
  const float* bb1   = (const float*)d_in[12];
  const float* bw2   = (const float*)d_in[13];
  const float* bb2   = (const float*)d_in[14];
  const float* ww1   = (const float*)d_in[15];
  const float* wb1   = (const float*)d_in[16];
  const float* ww2   = (const float*)d_in[17];
  const float* wb2   = (const float*)d_in[18];

  int*   starts = (int*)d_ws;                         // 4097 ints = 16388 B
  float* pooled = (float*)((char*)d_ws + 32768);      // B*H floats (no overlap!)
  float* out    = (float*)d_out;

  k_bounds<<<(N_NODES / 256) + 1, 256, 0, stream>>>(bb, starts, N_NODES, BATCH);
  k_fused<<<BATCH, 256, 0, stream>>>(ball, starts, aw1, ab1, aw2, ab2, pooled);
  k_combine<<<BATCH / 8, 128, 0, stream>>>(query, pooled, cw, cb, lg, lbeta,
                                           bw1, bb1, bw2, bb2, ww1, wb1, ww2, wb2, out);
}